// Round 6
// baseline (43.090 us; speedup 1.0000x reference)
//
#include <hip/hip_runtime.h>
#include <math.h>

#define BB 2
#define PP 4096
#define CC 64
#define SZ 128
#define KK 8

// radius = 1.5/128*2 = 0.0234375 (exact); r^2 = 9*2^-14 (exact)
#define R2f 0.00054931640625f
// margin: ring(1px=0.015625) + radius(0.0234375) + f32 slack -> 0.040
#define MARG 0.040f
#define SEGCAP 96         // per-wave segment cap (mean ~11, +20 sigma safe)
#define NTILE 512         // B * 16 * 16

// ---- single fused kernel: bin + rasterize + weights + composite + bg -------
__global__ __launch_bounds__(256) void mega_kernel(const float* __restrict__ pts,
                                                   const float* __restrict__ src,
                                                   float* __restrict__ out,
                                                   float* __restrict__ bgout) {
    const int tidb = threadIdx.x;
    const int wave = tidb >> 6;              // 0..3
    const int lane = tidb & 63;
    const int bid  = blockIdx.x;             // 0..511
    const int b    = bid >> 8;
    const int tile = bid & 255;
    const int ty = tile >> 4, tx = tile & 15;
    const int w0 = tx * 8, h0 = ty * 8;

    // conservative bounds in flipped NDC covering tile + 1px ring + radius
    const float xhi = 1.0f - (2 * w0 + 1)       * (1.0f / 128.0f) + MARG;
    const float xlo = 1.0f - (2 * (w0 + 7) + 1) * (1.0f / 128.0f) - MARG;
    const float yhi = 1.0f - (2 * h0 + 1)       * (1.0f / 128.0f) + MARG;
    const float ylo = 1.0f - (2 * (h0 + 7) + 1) * (1.0f / 128.0f) - MARG;

    __shared__ float sx[4][SEGCAP], sy[4][SEGCAP], sz[4][SEGCAP];
    __shared__ int   si[4][SEGCAP];
    __shared__ int   scnt[4];
    __shared__ float wl[64][KK];     // per-pixel weights
    __shared__ int   il[64][KK];     // per-pixel indices (-1 = empty)
    __shared__ float bgl[100];       // 10x10 bg0 patch (1 = empty pixel)

    const float* pb = pts + b * (PP * 3);

    // ---- phase A: per-wave ordered ballot compaction over its index quarter
    {
        int cnt = 0;
        const int pbase = wave * (PP / 4);
#pragma unroll 4
        for (int it = 0; it < (PP / 4); it += 64) {
            const int p = pbase + it + lane;
            const float px = pb[p * 3 + 0];
            const float py = pb[p * 3 + 1];
            const float pz = pb[p * 3 + 2];
            const float fx = -px, fy = -py;     // flipped coords (exact)
            const bool pred = (pz > 0.0f) && (fx >= xlo) && (fx <= xhi)
                                          && (fy >= ylo) && (fy <= yhi);
            const unsigned long long m = __ballot(pred);
            const int pos = cnt + __popcll(m & ((1ull << lane) - 1ull));
            if (pred && pos < SEGCAP) {
                sx[wave][pos] = px; sy[wave][pos] = py;
                sz[wave][pos] = pz; si[wave][pos] = p;
            }
            cnt += __popcll(m);
        }
        if (lane == 0) scnt[wave] = (cnt > SEGCAP) ? SEGCAP : cnt;
    }
    __syncthreads();

    // ---- phase B: wave 0 -> K-buffer + weights for 64 pixels;
    //               wave 1 -> bg0 for the 10x10 patch (incl. ring)
    if (wave == 0) {
        const int w = w0 + (lane & 7);
        const int h = h0 + (lane >> 3);
        const float gx = 1.0f - (2 * w + 1) * (1.0f / 128.0f);
        const float gy = 1.0f - (2 * h + 1) * (1.0f / 128.0f);

        float zk[KK], dk[KK];
        int ik[KK];
#pragma unroll
        for (int s = 0; s < KK; ++s) { zk[s] = INFINITY; dk[s] = 0.0f; ik[s] = -1; }

#pragma unroll 1
        for (int sg = 0; sg < 4; ++sg) {
            const int n = scnt[sg];
            for (int j = 0; j < n; ++j) {
                const float dx = __fadd_rn(gx, sx[sg][j]);   // ref: gx - (-px)
                const float dy = __fadd_rn(gy, sy[sg][j]);
                const float d2 = __fadd_rn(__fmul_rn(dx, dx), __fmul_rn(dy, dy));
                const float z  = sz[sg][j];
                if (d2 < R2f && z > 0.0f) {
                    float zn = z, dn = d2;
                    int   in_ = si[sg][j];
#pragma unroll
                    for (int s = 0; s < KK; ++s) {
                        if (zn < zk[s]) {   // strict <: lower idx first on z-tie
                            float tz = zk[s]; zk[s] = zn; zn = tz;
                            float td = dk[s]; dk[s] = dn; dn = td;
                            int   ti = ik[s]; ik[s] = in_; in_ = ti;
                        }
                    }
                }
            }
        }
        float T = 1.0f;
#pragma unroll
        for (int s = 0; s < KK; ++s) {
            float a = 0.0f;
            if (ik[s] >= 0) {
                float dn = dk[s] / R2f;
                dn = fminf(fmaxf(dn, 0.001f), 1.0f);
                a = 1.0f - sqrtf(dn);
            }
            wl[lane][s] = a * T;
            T = T * (1.0f - a);
            il[lane][s] = ik[s];
        }
    } else if (wave == 1) {
        // each lane: patch cells lane and lane+64 (100 cells total)
#pragma unroll 2
        for (int cell = lane; cell < 100; cell += 64) {
            const int i = cell / 10, j = cell - 10 * i;   // patch coords
            const int h = h0 - 1 + i, w = w0 - 1 + j;
            float v = 0.0f;                               // OOB -> 0
            if (h >= 0 && h < SZ && w >= 0 && w < SZ) {
                const float gx = 1.0f - (2 * w + 1) * (1.0f / 128.0f);
                const float gy = 1.0f - (2 * h + 1) * (1.0f / 128.0f);
                int hit = 0;
#pragma unroll 1
                for (int sg = 0; sg < 4 && !hit; ++sg) {
                    const int n = scnt[sg];
                    for (int jj = 0; jj < n; ++jj) {
                        const float dx = __fadd_rn(gx, sx[sg][jj]);
                        const float dy = __fadd_rn(gy, sy[sg][jj]);
                        const float d2 = __fadd_rn(__fmul_rn(dx, dx), __fmul_rn(dy, dy));
                        if (d2 < R2f && sz[sg][jj] > 0.0f) { hit = 1; break; }
                    }
                }
                v = hit ? 0.0f : 1.0f;                    // 1 = background
            }
            bgl[cell] = v;
        }
    }
    __syncthreads();

    // ---- phase C: composite. thread t: channel c = t>>2, rows 2*(t&3), +1.
    {
        const int c  = tidb >> 2;
        const int r0 = (tidb & 3) * 2;
        const float* srow = src + (size_t)(b * CC + c) * PP;
#pragma unroll 2
        for (int rr = 0; rr < 2; ++rr) {
            const int dh = r0 + rr;
            float acc[8];
#pragma unroll
            for (int dw = 0; dw < 8; ++dw) acc[dw] = 0.0f;
#pragma unroll
            for (int dw = 0; dw < 8; ++dw) {
                const int pl = dh * 8 + dw;
#pragma unroll
                for (int s = 0; s < KK; ++s) {
                    const int id = il[pl][s];
                    if (id < 0) break;           // valid slots form a prefix
                    acc[dw] = fmaf(wl[pl][s], srow[id], acc[dw]);
                }
            }
            float* op = out + (((size_t)(b * CC + c) << 14) | ((h0 + dh) << 7) | w0);
            *(float4*)op       = make_float4(acc[0], acc[1], acc[2], acc[3]);
            *(float4*)(op + 4) = make_float4(acc[4], acc[5], acc[6], acc[7]);
        }
    }

    // ---- bg: threads 0..63 emit dilated background for their pixel
    if (tidb < 64) {
        const int dw = tidb & 7, dh = tidb >> 3;
        float m = 0.0f;
#pragma unroll
        for (int di = 0; di < 3; ++di)
#pragma unroll
            for (int dj = 0; dj < 3; ++dj)
                m = fmaxf(m, bgl[(dh + di) * 10 + (dw + dj)]);
        bgout[(b << 14) | ((h0 + dh) << 7) | (w0 + dw)] = (m > 0.0f) ? 1.0f : 0.0f;
    }
}

extern "C" void kernel_launch(void* const* d_in, const int* in_sizes, int n_in,
                              void* d_out, int out_size, void* d_ws, size_t ws_size,
                              hipStream_t stream) {
    const float* pts = (const float*)d_in[0];   // [B,P,3]
    const float* src = (const float*)d_in[1];   // [B,C,P]
    float* out = (float*)d_out;                 // [B,C,H,W] then bg [B,H,W]

    mega_kernel<<<NTILE, 256, 0, stream>>>(pts, src, out, out + BB * CC * SZ * SZ);
}